// Round 1
// baseline (381.745 us; speedup 1.0000x reference)
//
#include <hip/hip_runtime.h>
#include <math.h>

#define N_NODES   65536
#define N_EDGES   1048576
#define KCUB      125
#define F_OUT     32
#define GRID_DIM  32
#define NUM_VOX   (GRID_DIM * GRID_DIM * GRID_DIM)

// ---------- monotonic float<->uint encoding for atomicMax on signed floats ----
__device__ __forceinline__ unsigned int enc_f32(float f) {
    unsigned int u = __float_as_uint(f);
    return (u & 0x80000000u) ? ~u : (u | 0x80000000u);
}
__device__ __forceinline__ float dec_f32(unsigned int e) {
    return (e & 0x80000000u) ? __uint_as_float(e ^ 0x80000000u)
                             : __uint_as_float(~e);
}

// ---------- kernel 1: per-edge spline message + scatter-add ------------------
// 32 lanes per edge; lane o handles output channel o.
__global__ __launch_bounds__(256) void edge_kernel(
    const float* __restrict__ x,         // [N,1]
    const int*   __restrict__ src,       // [E]
    const int*   __restrict__ dst,       // [E]
    const float* __restrict__ pseudo,    // [E,3]
    const float* __restrict__ W,         // [125,1,32]
    float* __restrict__ agg,             // [N,32]
    float* __restrict__ deg,             // [N]
    int E)
{
    __shared__ float sW[KCUB * F_OUT];   // 16000 B
    for (int i = threadIdx.x; i < KCUB * F_OUT; i += blockDim.x)
        sW[i] = W[i];
    __syncthreads();

    int gid = blockIdx.x * blockDim.x + threadIdx.x;
    int e = gid >> 5;
    int o = gid & 31;
    if (e >= E) return;

    int   d  = dst[e];
    float xj = x[src[e]];

    float p0 = pseudo[e * 3 + 0] * 4.0f;
    float p1 = pseudo[e * 3 + 1] * 4.0f;
    float p2 = pseudo[e * 3 + 2] * 4.0f;

    float i0 = fminf(fmaxf(floorf(p0), 0.0f), 3.0f);
    float i1 = fminf(fmaxf(floorf(p1), 0.0f), 3.0f);
    float i2 = fminf(fmaxf(floorf(p2), 0.0f), 3.0f);
    float f0 = p0 - i0, f1 = p1 - i1, f2 = p2 - i2;
    float g0 = 1.0f - f0, g1 = 1.0f - f1, g2 = 1.0f - f2;

    int base = ((int)i0 + 5 * (int)i1 + 25 * (int)i2) * F_OUT + o;

    // 8 corners: dim0 stride 1, dim1 stride 5, dim2 stride 25 (in kernel idx)
    float coeff;
    coeff  = (g0 * g1 * g2) * sW[base];
    coeff += (f0 * g1 * g2) * sW[base +  1 * F_OUT];
    coeff += (g0 * f1 * g2) * sW[base +  5 * F_OUT];
    coeff += (f0 * f1 * g2) * sW[base +  6 * F_OUT];
    coeff += (g0 * g1 * f2) * sW[base + 25 * F_OUT];
    coeff += (f0 * g1 * f2) * sW[base + 26 * F_OUT];
    coeff += (g0 * f1 * f2) * sW[base + 30 * F_OUT];
    coeff += (f0 * f1 * f2) * sW[base + 31 * F_OUT];

    atomicAdd(&agg[d * F_OUT + o], xj * coeff);
    if (o == 0) atomicAdd(&deg[d], 1.0f);
}

// ---------- kernel 2: node epilogue + voxel scatter-max ----------------------
__global__ __launch_bounds__(256) void node_kernel(
    const float* __restrict__ agg,       // [N,32]
    const float* __restrict__ deg,       // [N]
    const float* __restrict__ x,         // [N,1]
    const float* __restrict__ W_root,    // [1,32]
    const float* __restrict__ bias,      // [32]
    const float* __restrict__ pos,       // [N,3]
    unsigned int* __restrict__ pooled,   // [NUM_VOX,32] encoded
    int Nn)
{
    int gid = blockIdx.x * blockDim.x + threadIdx.x;
    int n = gid >> 5;
    int o = gid & 31;
    if (n >= Nn) return;

    float dg = fmaxf(deg[n], 1.0f);
    float h  = agg[n * F_OUT + o] / dg + x[n] * W_root[o] + bias[o];
    h = (h > 0.0f) ? h : expm1f(h);   // ELU, alpha=1

    int vx = min(max((int)floorf(pos[n * 3 + 0] * (float)GRID_DIM), 0), GRID_DIM - 1);
    int vy = min(max((int)floorf(pos[n * 3 + 1] * (float)GRID_DIM), 0), GRID_DIM - 1);
    int vz = min(max((int)floorf(pos[n * 3 + 2] * (float)GRID_DIM), 0), GRID_DIM - 1);
    int vidx = vx + GRID_DIM * vy + GRID_DIM * GRID_DIM * vz;

    atomicMax(&pooled[vidx * F_OUT + o], enc_f32(h));
}

// ---------- kernel 3: decode, empty voxels -> 0 ------------------------------
__global__ __launch_bounds__(256) void finalize_kernel(
    const unsigned int* __restrict__ pooled,
    float* __restrict__ out, int M)
{
    int i = blockIdx.x * blockDim.x + threadIdx.x;
    if (i >= M) return;
    unsigned int u = pooled[i];
    out[i] = (u == 0u) ? 0.0f : dec_f32(u);
}

extern "C" void kernel_launch(void* const* d_in, const int* in_sizes, int n_in,
                              void* d_out, int out_size, void* d_ws, size_t ws_size,
                              hipStream_t stream) {
    const float* x       = (const float*)d_in[0];
    const int*   ei      = (const int*)  d_in[1];
    const float* pseudo  = (const float*)d_in[2];
    const float* pos     = (const float*)d_in[3];
    const float* W       = (const float*)d_in[4];
    const float* W_root  = (const float*)d_in[5];
    const float* bias    = (const float*)d_in[6];
    float* out = (float*)d_out;

    const int E = in_sizes[1] / 2;
    const int Nn = in_sizes[0];           // F_IN == 1

    // workspace layout
    float*        agg    = (float*)d_ws;                              // N*32 f32  (8 MB)
    float*        deg    = (float*)((char*)d_ws + (size_t)Nn * F_OUT * 4);  // N f32
    unsigned int* pooled = (unsigned int*)((char*)deg + (size_t)Nn * 4);    // NUM_VOX*32 u32
    size_t zero_bytes = (size_t)Nn * F_OUT * 4 + (size_t)Nn * 4 + (size_t)NUM_VOX * F_OUT * 4;

    hipMemsetAsync(d_ws, 0, zero_bytes, stream);

    {
        int total = E * F_OUT;
        int blocks = (total + 255) / 256;
        edge_kernel<<<blocks, 256, 0, stream>>>(x, ei, ei + E, pseudo, W, agg, deg, E);
    }
    {
        int total = Nn * F_OUT;
        int blocks = (total + 255) / 256;
        node_kernel<<<blocks, 256, 0, stream>>>(agg, deg, x, W_root, bias, pos, pooled, Nn);
    }
    {
        int total = NUM_VOX * F_OUT;
        int blocks = (total + 255) / 256;
        finalize_kernel<<<blocks, 256, 0, stream>>>(pooled, out, out_size < total ? out_size : total);
    }
}